// Round 3
// baseline (185.478 us; speedup 1.0000x reference)
//
#include <hip/hip_runtime.h>

// CPRPackedLinear: out(64x11008) = xperm[:, :1024] @ deq6(W_high) + xperm[:, 1024:] @ deq5(W_low) + bias
// R3: R2's crash traced to the non-standard asm lgkmcnt-barrier + cross-barrier
// in-flight loads. New structure keeps the pipelining with plain __syncthreads():
//   dq_store(buf); __syncthreads(); load(t+1); mfma(buf,t)
// -> no vmem outstanding at the barrier (vmcnt(0) drain is free), load latency
// hidden behind the MFMA phase, waits absorbed per-wave at next dq_store.
// Single register slot, dwordx4 packed loads, pk-fp16 dequant, XOR-swizzled
// fragment LDS, HIGH/LOW split kernels, grid total (172,8).

#define NFEAT 11008
#define KTOT  4096

typedef _Float16 half8 __attribute__((ext_vector_type(8)));
typedef _Float16 half2 __attribute__((ext_vector_type(2)));
typedef float    f32x4 __attribute__((ext_vector_type(4)));
typedef int      i32x4 __attribute__((ext_vector_type(4)));

union H8 { half8 v; half2 h[4]; _Float16 e[8]; };

// (1024+a, 1024+b) as packed fp16 (exact for 0..255), then (h-off)*s in pk-f16.
// (sub then mul: v-off exact in fp16, single rounding on the product.)
__device__ __forceinline__ half2 dq2(int a, int b, half2 off, half2 s) {
    unsigned u = 0x64006400u | (unsigned)a | ((unsigned)b << 16);
    half2 h = __builtin_bit_cast(half2, u);
    return (h - off) * s;
}

// ---------------- prep: x_perm -> fp16 in MFMA A-fragment layout ----------------
// xfrag chunk u = (sg*4 + mt)*64 + lane holds 8 halves:
//   x[m = mt*16 + (lane&15)][ col[k = sg*32 + (lane>>4)*8 + j] ], j=0..7
__global__ __launch_bounds__(256) void prep_xfrag(const float* __restrict__ x,
                                                  const int* __restrict__ col,
                                                  _Float16* __restrict__ xfrag) {
    int u  = blockIdx.x * 256 + threadIdx.x;   // 0..32767
    int l  = u & 63;
    int mt = (u >> 6) & 3;
    int s  = u >> 8;
    int m  = mt * 16 + (l & 15);
    int kb = s * 32 + ((l >> 4) << 3);
    H8 w;
#pragma unroll
    for (int j = 0; j < 8; ++j)
        w.e[j] = (_Float16)x[m * KTOT + col[kb + j]];
    *(half8*)(xfrag + (size_t)u * 8) = w.v;
}

// ---------------- main GEMM (one region per instantiation) ----------------
// grid.x = 172 (64-col n-tiles); grid.y = chunks of (titers*128) region-local k.
// sg_off = region global k start >> 5 (0 for high, 32 for low).
template <bool HIGH>
__global__ __launch_bounds__(256, 4) void gemm_kernel(const int* __restrict__ W,
                                                      const float* __restrict__ S,
                                                      const _Float16* __restrict__ xfrag,
                                                      float* __restrict__ dst,
                                                      int titers, int sg_off,
                                                      int atomic_mode) {
    const int n0   = blockIdx.x * 64;
    const int tid  = threadIdx.x;
    const int lane = tid & 63;
    const int wave = tid >> 6;
    const int cg   = tid & 15;   // col-group: cols n0+cg*4 .. +3
    const int kg   = tid >> 4;   // k-run: k = kg*8 .. +7 within the 128-k tile
    const int kgl  = kg & 3;
    const int colb = n0 + cg * 4;
    const int kbase = blockIdx.y * titers * 128;   // region-local

    // double-buffered fragment-ready LDS, 16B chunks XOR-swizzled by (chunk>>4)&3
    __shared__ _Float16 lds[2 * 8192];
    const int wchunk0 = ((cg >> 2) * 4 + (kg >> 2)) * 64 + kgl * 16 + (cg & 3) * 4;
    const int laneX   = lane ^ (lane >> 4);

    f32x4 acc[4];
#pragma unroll
    for (int i = 0; i < 4; ++i) acc[i] = (f32x4){0.f, 0.f, 0.f, 0.f};

    i32x4 R[6];
    f32x4 s4;

    auto load_tile = [&](int t) {
        const int kb = kbase + t * 128;
        if constexpr (HIGH) {
            const int* p = W + (size_t)((kb >> 2) * 3 + kg * 6) * NFEAT + colb;
#pragma unroll
            for (int r = 0; r < 6; ++r) R[r] = *(const i32x4*)(p + (size_t)r * NFEAT);
        } else {
            const int* p = W + (size_t)((kb >> 3) * 5 + kg * 5) * NFEAT + colb;
#pragma unroll
            for (int r = 0; r < 5; ++r) R[r] = *(const i32x4*)(p + (size_t)r * NFEAT);
        }
        s4 = *(const f32x4*)(S + (size_t)(kb >> 7) * NFEAT + colb);
    };

    auto dq_store = [&](int buf) {
        _Float16* base = lds + (buf << 13);
        const _Float16 offv = HIGH ? (_Float16)1055.0f : (_Float16)1039.0f;
        const half2 off = {offv, offv};
#pragma unroll
        for (int cc = 0; cc < 4; ++cc) {
            int v0, v1, v2, v3, v4, v5, v6, v7;
            if constexpr (HIGH) {
                int b0 = R[0][cc], b1 = R[1][cc], b2 = R[2][cc],
                    b3 = R[3][cc], b4 = R[4][cc], b5 = R[5][cc];
                v0 = b0 & 63;
                v1 = ((b0 >> 6) & 3) | ((b1 & 15) << 2);
                v2 = ((b1 >> 4) & 15) | ((b2 & 3) << 4);
                v3 = (b2 >> 2) & 63;
                v4 = b3 & 63;
                v5 = ((b3 >> 6) & 3) | ((b4 & 15) << 2);
                v6 = ((b4 >> 4) & 15) | ((b5 & 3) << 4);
                v7 = (b5 >> 2) & 63;
            } else {
                int b0 = R[0][cc], b1 = R[1][cc], b2 = R[2][cc],
                    b3 = R[3][cc], b4 = R[4][cc];
                v0 = b0 & 31;
                v1 = ((b0 >> 5) & 7) | ((b1 & 3) << 3);
                v2 = (b1 >> 2) & 31;
                v3 = ((b1 >> 7) & 1) | ((b2 & 15) << 1);
                v4 = ((b2 >> 4) & 15) | ((b3 & 1) << 4);
                v5 = (b3 >> 1) & 31;
                v6 = ((b3 >> 6) & 3) | ((b4 & 7) << 2);
                v7 = (b4 >> 3) & 31;
            }
            _Float16 sc = (_Float16)s4[cc];
            half2 s2 = {sc, sc};
            H8 w;
            w.h[0] = dq2(v0, v1, off, s2);
            w.h[1] = dq2(v2, v3, off, s2);
            w.h[2] = dq2(v4, v5, off, s2);
            w.h[3] = dq2(v6, v7, off, s2);
            *(half8*)(base + (size_t)(wchunk0 + (cc ^ kgl)) * 8) = w.v;
        }
    };

    auto do_mfma = [&](int buf, int t) {
        const _Float16* Bb = lds + (buf << 13);
        const int sg = sg_off + (kbase >> 5) + t * 4;
        half8 a[4];
#pragma unroll
        for (int q = 0; q < 4; ++q)
            a[q] = *(const half8*)(xfrag + (size_t)(((sg + q) * 4 + wave) * 64 + lane) * 8);
#pragma unroll
        for (int q = 0; q < 4; ++q) {
#pragma unroll
            for (int nt = 0; nt < 4; ++nt) {
                half8 b = *(const half8*)(Bb + (size_t)((nt * 4 + q) * 64 + laneX) * 8);
                acc[nt] = __builtin_amdgcn_mfma_f32_16x16x32_f16(a[q], b, acc[nt], 0, 0, 0);
            }
        }
    };

    load_tile(0);
    int buf = 0;
    for (int t = 0; t < titers; ++t) {
        dq_store(buf);           // consumes R,s4 (vmcnt wait lands here, per-wave)
        __syncthreads();         // no vmem outstanding -> drain is free
        if (t + 1 < titers) load_tile(t + 1);   // in flight during MFMA phase
        do_mfma(buf, t);
        buf ^= 1;
        // single barrier per tile: writes at t+2 to this buffer are fenced by
        // barrier t+1, whose lgkmcnt(0) drains all reads issued at tile t.
    }

    // ---- epilogue: D row = wave*16 + (lane>>4)*4 + r, col = n0 + nt*16 + (lane&15) ----
    const int rb = wave * 16 + ((lane >> 4) << 2);
    const int cb = lane & 15;
    if (atomic_mode) {
#pragma unroll
        for (int j = 0; j < 4; ++j)
#pragma unroll
            for (int r = 0; r < 4; ++r)
                atomicAdd(&dst[(size_t)(rb + r) * NFEAT + n0 + j * 16 + cb], acc[j][r]);
    } else {
        float* o = dst + (size_t)blockIdx.y * 64 * NFEAT;
#pragma unroll
        for (int j = 0; j < 4; ++j)
#pragma unroll
            for (int r = 0; r < 4; ++r)
                o[(size_t)(rb + r) * NFEAT + n0 + j * 16 + cb] = acc[j][r];
    }
}

// ---------------- reduce: out = bias + sum_p partial[p] ----------------
__global__ __launch_bounds__(256) void reduce_out(const float* __restrict__ part,
                                                  const float* __restrict__ bias,
                                                  float* __restrict__ out, int P) {
    const int idx = blockIdx.x * 256 + threadIdx.x;   // 0..176127 (f32x4 units)
    const int f   = idx * 4;
    const int n   = f % NFEAT;                        // NFEAT%4==0 -> same row
    f32x4 s = *(const f32x4*)(bias + n);
    for (int p = 0; p < P; ++p)
        s += *(const f32x4*)(part + (size_t)p * 704512 + f);
    *(f32x4*)(out + f) = s;
}

__global__ __launch_bounds__(256) void init_bias(const float* __restrict__ bias,
                                                 float* __restrict__ out) {
    const int idx = blockIdx.x * 256 + threadIdx.x;   // 0..704511
    out[idx] = bias[idx % NFEAT];
}

extern "C" void kernel_launch(void* const* d_in, const int* in_sizes, int n_in,
                              void* d_out, int out_size, void* d_ws, size_t ws_size,
                              hipStream_t stream) {
    const float* x    = (const float*)d_in[0];
    const int*   Wh   = (const int*)d_in[1];
    const int*   Wl   = (const int*)d_in[2];
    const float* sh   = (const float*)d_in[3];
    const float* sl   = (const float*)d_in[4];
    const int*   col  = (const int*)d_in[5];
    const float* bias = (const float*)d_in[6];
    float* out = (float*)d_out;

    _Float16* xfrag = (_Float16*)d_ws;                         // 512 KB
    const size_t xb      = (size_t)64 * KTOT * sizeof(_Float16);
    const size_t pstride = (size_t)64 * NFEAT;                 // floats per partial

    prep_xfrag<<<128, 256, 0, stream>>>(x, col, xfrag);

    if (ws_size >= xb + 8 * pstride * sizeof(float)) {
        float* part = (float*)((char*)d_ws + xb);
        gemm_kernel<true><<<dim3(172, 2), 256, 0, stream>>>(Wh, sh, xfrag, part, 4, 0, 0);
        gemm_kernel<false><<<dim3(172, 6), 256, 0, stream>>>(Wl, sl, xfrag,
                                                             part + 2 * pstride, 4, 32, 0);
        reduce_out<<<688, 256, 0, stream>>>(part, bias, out, 8);
    } else if (ws_size >= xb + 4 * pstride * sizeof(float)) {
        float* part = (float*)((char*)d_ws + xb);
        gemm_kernel<true><<<dim3(172, 1), 256, 0, stream>>>(Wh, sh, xfrag, part, 8, 0, 0);
        gemm_kernel<false><<<dim3(172, 3), 256, 0, stream>>>(Wl, sl, xfrag,
                                                             part + pstride, 8, 32, 0);
        reduce_out<<<688, 256, 0, stream>>>(part, bias, out, 4);
    } else {
        init_bias<<<2752, 256, 0, stream>>>(bias, out);
        gemm_kernel<true><<<dim3(172, 2), 256, 0, stream>>>(Wh, sh, xfrag, out, 4, 0, 1);
        gemm_kernel<false><<<dim3(172, 6), 256, 0, stream>>>(Wl, sl, xfrag, out, 4, 32, 1);
    }
}